// Round 1
// baseline (1244.129 us; speedup 1.0000x reference)
//
#include <hip/hip_runtime.h>
#include <math.h>

#define NNODE 2048
#define MCLUS 2048
#define KNBR  32
#define CDIM  256
#define HHEAD 8

__device__ __forceinline__ float sigf(float x) { return 1.0f / (1.0f + __expf(-x)); }

// ---------------- K0: detect attn_mask storage layout ----------------
// mode 0 = int32 (0/1), mode 1 = raw bool bytes, mode 2 = float32 (0.0/1.0)
__global__ void k0_detect(const unsigned int* __restrict__ mw, int* __restrict__ flag) {
    __shared__ int votes[2];
    int t = threadIdx.x;
    if (t < 2) votes[t] = 0;
    __syncthreads();
    int vb = 0, vf = 0;
    for (int i = t; i < (NNODE * KNBR) / 4; i += blockDim.x) {
        unsigned int w = mw[i];
        if (w == 0x3F800000u) vf = 1;
        else if (w > 1u) vb = 1;
    }
    if (vb) atomicOr(&votes[0], 1);
    if (vf) atomicOr(&votes[1], 1);
    __syncthreads();
    if (t == 0) flag[0] = votes[1] ? 2 : (votes[0] ? 1 : 0);
}

__device__ __forceinline__ bool edge_masked(const void* mp, int mode, int e) {
    if (mode == 1) return ((const unsigned char*)mp)[e] != 0;
    if (mode == 2) return ((const float*)mp)[e] != 0.0f;
    return ((const int*)mp)[e] != 0;
}

// ---------------- K1: so3_linear for q (nodes) and key (clusters) ----------------
// virtual rows per l over (N+M) sources; 32 rows/block, 256 threads.
__global__ __launch_bounds__(256) void k1_so3qk(
    const float* __restrict__ nodei, const float* __restrict__ clus,
    const float* __restrict__ W_dot, const float* __restrict__ b_dot,
    float* __restrict__ q_ws, float* __restrict__ key_ws)
{
    __shared__ __align__(16) float X[32][256];
    __shared__ int rx[32], rmm[32];
    int b = blockIdx.x, t = threadIdx.x;
    int l, vr0, nm, moff;
    if (b < 128)      { l = 0; vr0 = b * 32;         nm = 1; moff = 0; }
    else if (b < 512) { l = 1; vr0 = (b - 128) * 32; nm = 3; moff = 1; }
    else              { l = 2; vr0 = (b - 512) * 32; nm = 5; moff = 4; }
    if (t < 32) {
        int vr = vr0 + t;
        rx[t] = vr / nm;
        rmm[t] = moff + vr % nm;
    }
    __syncthreads();
    for (int e = t; e < 32 * 256; e += 256) {
        int r = e >> 8, c = e & 255;
        int x = rx[r], m = rmm[r];
        const float* src = (x < NNODE) ? (nodei + ((size_t)x * 9 + m) * 256)
                                       : (clus + ((size_t)(x - NNODE) * 9 + m) * 256);
        X[r][c] = src[c];
    }
    __syncthreads();
    int d = t & 31, rg = t >> 5;
    int r0 = rg * 4;
    const float4* wrow = (const float4*)(W_dot + ((size_t)l * 32 + d) * 256);
    float acc[4];
    float bd = (l == 0) ? b_dot[d] : 0.0f;
#pragma unroll
    for (int jj = 0; jj < 4; ++jj) acc[jj] = bd;
    for (int c4 = 0; c4 < 64; ++c4) {
        float4 w = wrow[c4];
#pragma unroll
        for (int jj = 0; jj < 4; ++jj) {
            float4 x4 = *(const float4*)&X[r0 + jj][c4 * 4];
            acc[jj] = fmaf(x4.x, w.x, fmaf(x4.y, w.y, fmaf(x4.z, w.z, fmaf(x4.w, w.w, acc[jj]))));
        }
    }
#pragma unroll
    for (int jj = 0; jj < 4; ++jj) {
        int r = r0 + jj;
        int x = rx[r], m = rmm[r];
        float* dst = (x < NNODE) ? (q_ws + ((size_t)x * 9 + m) * 32)
                                 : (key_ws + ((size_t)(x - NNODE) * 9 + m) * 32);
        dst[d] = acc[jj];
    }
}

// ---------------- radial MLP layers 1+2 (Linear->LN->SiLU twice) ----------------
// all 256 threads call: thread = (kk edge, j hidden). Result left in hb[kk][j].
__device__ __forceinline__ void radial12(
    int kk, int j, const float* xe_row,
    float (*ha)[16], float (*hb)[16],
    const float* __restrict__ w1, const float* __restrict__ b1,
    const float* __restrict__ g1, const float* __restrict__ be1,
    const float* __restrict__ w2, const float* __restrict__ b2,
    const float* __restrict__ g2, const float* __restrict__ be2)
{
    float acc = b1[j];
    const float4* wr = (const float4*)(w1 + j * 416);
    const float4* xr = (const float4*)xe_row;
#pragma unroll 8
    for (int i4 = 0; i4 < 104; ++i4) {
        float4 a = xr[i4], w = wr[i4];
        acc = fmaf(a.x, w.x, fmaf(a.y, w.y, fmaf(a.z, w.z, fmaf(a.w, w.w, acc))));
    }
    ha[kk][j] = acc;
    __syncthreads();
    {
        float mu = 0.0f, var = 0.0f;
#pragma unroll
        for (int i = 0; i < 16; ++i) mu += ha[kk][i];
        mu *= 0.0625f;
#pragma unroll
        for (int i = 0; i < 16; ++i) { float dd = ha[kk][i] - mu; var = fmaf(dd, dd, var); }
        var *= 0.0625f;
        float y = (ha[kk][j] - mu) * rsqrtf(var + 1e-5f) * g1[j] + be1[j];
        hb[kk][j] = y * sigf(y);
    }
    __syncthreads();
    {
        float acc2 = b2[j];
#pragma unroll
        for (int i = 0; i < 16; ++i) acc2 = fmaf(hb[kk][i], w2[j * 16 + i], acc2);
        ha[kk][j] = acc2;
    }
    __syncthreads();
    {
        float mu = 0.0f, var = 0.0f;
#pragma unroll
        for (int i = 0; i < 16; ++i) mu += ha[kk][i];
        mu *= 0.0625f;
#pragma unroll
        for (int i = 0; i < 16; ++i) { float dd = ha[kk][i] - mu; var = fmaf(dd, dd, var); }
        var *= 0.0625f;
        float y = (ha[kk][j] - mu) * rsqrtf(var + 1e-5f) * g2[j] + be2[j];
        hb[kk][j] = y * sigf(y);
    }
    __syncthreads();
}

// ---------------- K2: per-node edge pipeline (x_edge, MLPs, m0, af, logits, vw) ----------------
__global__ __launch_bounds__(256) void k2_edge(
    const float* __restrict__ attn_weight, const void* __restrict__ mask,
    const int* __restrict__ mflag,
    const int* __restrict__ f_idx, const float* __restrict__ edge_vec,
    const int* __restrict__ atom_num, const float* __restrict__ tgt_emb,
    const float* __restrict__ clus,
    const float* __restrict__ q_ws, const float* __restrict__ key_ws,
    const float* __restrict__ rm0_w1, const float* __restrict__ rm0_b1,
    const float* __restrict__ rm0_g1, const float* __restrict__ rm0_be1,
    const float* __restrict__ rm0_w2, const float* __restrict__ rm0_b2,
    const float* __restrict__ rm0_g2, const float* __restrict__ rm0_be2,
    const float* __restrict__ rm0_w3, const float* __restrict__ rm0_b3,
    const float* __restrict__ fcw, const float* __restrict__ fcb,
    const float* __restrict__ an_g, const float* __restrict__ an_b,
    const float* __restrict__ alpha_dot,
    const float* __restrict__ rv_w1, const float* __restrict__ rv_b1,
    const float* __restrict__ rv_g1, const float* __restrict__ rv_be1,
    const float* __restrict__ rv_w2, const float* __restrict__ rv_b2,
    const float* __restrict__ rv_g2, const float* __restrict__ rv_be2,
    const float* __restrict__ rv_w3, const float* __restrict__ rv_b3,
    float* __restrict__ logits_g, float* __restrict__ vw_g)
{
    __shared__ __align__(16) float xe[16][420];     // x_edge, 16 edges per pass
    __shared__ __align__(16) float kaf[16 * 288];   // union: keyr[16][288] then af[16][260]
    __shared__ __align__(16) float mwa[16][196];    // m0 * ew
    __shared__ float tgt_s[128];
    __shared__ float qn[288];
    __shared__ float ha[16][16], hb[16][16];
    __shared__ float sh_s[16][12];
    __shared__ int idxk[16], maskk[16];

    int n = blockIdx.x, t = threadIdx.x;
    int mode = mflag[0];
    int an = atom_num[n];
    for (int i = t; i < 128; i += 256) tgt_s[i] = tgt_emb[an * 128 + i];
    for (int i = t; i < 288; i += 256) qn[i] = q_ws[(size_t)n * 288 + i];

    int kk = t >> 4, j = t & 15;

    for (int pass = 0; pass < 2; ++pass) {
        int kbase = pass * 16;
        __syncthreads();
        if (t < 16) {
            int e = n * KNBR + kbase + t;
            idxk[t] = f_idx[e];
            maskk[t] = edge_masked(mask, mode, e) ? 1 : 0;
            float vx = edge_vec[(size_t)e * 3 + 0];
            float vy = edge_vec[(size_t)e * 3 + 1];
            float vz = edge_vec[(size_t)e * 3 + 2];
            float inv = 1.0f / (sqrtf(vx * vx + vy * vy + vz * vz) + 1e-12f);
            float x = vx * inv, y = vy * inv, z = vz * inv;
            sh_s[t][0] = 0.28209479177387814f;
            sh_s[t][1] = 0.4886025119029199f * y;
            sh_s[t][2] = 0.4886025119029199f * z;
            sh_s[t][3] = 0.4886025119029199f * x;
            sh_s[t][4] = 1.0925484305920792f * x * y;
            sh_s[t][5] = 1.0925484305920792f * y * z;
            sh_s[t][6] = 0.31539156525252005f * (3.0f * z * z - 1.0f);
            sh_s[t][7] = 1.0925484305920792f * x * z;
            sh_s[t][8] = 0.5462742152960396f * (x * x - y * y);
        }
        __syncthreads();
        // build x_edge = [aw(32) | tgt(128) | cl_scal(256)]
        for (int e2 = t; e2 < 16 * 32; e2 += 256) {
            int ek = e2 >> 5, i = e2 & 31;
            xe[ek][i] = maskk[ek] ? 0.0f
                                  : attn_weight[((size_t)(n * KNBR + kbase + ek)) * 32 + i];
        }
        for (int e2 = t; e2 < 16 * 128; e2 += 256) {
            int ek = e2 >> 7, i = e2 & 127;
            xe[ek][32 + i] = tgt_s[i];
        }
        for (int e2 = t; e2 < 16 * 256; e2 += 256) {
            int ek = e2 >> 8, i = e2 & 255;
            xe[ek][160 + i] = clus[(size_t)idxk[ek] * 2304 + i];
        }
        float* keyr = kaf;
        for (int e2 = t; e2 < 16 * 288; e2 += 256) {
            int ek = e2 / 288, i = e2 - ek * 288;
            keyr[ek * 288 + i] = key_ws[(size_t)idxk[ek] * 288 + i];
        }
        __syncthreads();

        // rm0 MLP (layers 1-2) -> hb
        radial12(kk, j, &xe[kk][0], ha, hb,
                 rm0_w1, rm0_b1, rm0_g1, rm0_be1, rm0_w2, rm0_b2, rm0_g2, rm0_be2);

        // rm0 layer3 (16->192) fused with m0 degree-dots: mwa = ew * m0
        for (int r = 0; r < 12; ++r) {
            int oi = t + r * 256;
            int ek = oi / 192, d = oi - ek * 192;
            float ew = rm0_b3[d];
#pragma unroll
            for (int i = 0; i < 16; ++i) ew = fmaf(hb[ek][i], rm0_w3[d * 16 + i], ew);
            int bb = d >> 5, c = d & 31;
            float m0v;
            if (bb == 0)      m0v = qn[c] * sh_s[ek][0];
            else if (bb == 1) m0v = qn[32 + c] * sh_s[ek][1] + qn[64 + c] * sh_s[ek][2]
                                  + qn[96 + c] * sh_s[ek][3];
            else if (bb == 2) m0v = qn[128 + c] * sh_s[ek][4] + qn[160 + c] * sh_s[ek][5]
                                  + qn[192 + c] * sh_s[ek][6] + qn[224 + c] * sh_s[ek][7]
                                  + qn[256 + c] * sh_s[ek][8];
            else if (bb == 3) m0v = keyr[ek * 288 + c] * sh_s[ek][0];
            else if (bb == 4) m0v = keyr[ek * 288 + 32 + c] * sh_s[ek][1]
                                  + keyr[ek * 288 + 64 + c] * sh_s[ek][2]
                                  + keyr[ek * 288 + 96 + c] * sh_s[ek][3];
            else              m0v = keyr[ek * 288 + 128 + c] * sh_s[ek][4]
                                  + keyr[ek * 288 + 160 + c] * sh_s[ek][5]
                                  + keyr[ek * 288 + 192 + c] * sh_s[ek][6]
                                  + keyr[ek * 288 + 224 + c] * sh_s[ek][7]
                                  + keyr[ek * 288 + 256 + c] * sh_s[ek][8];
            mwa[ek][d] = ew * m0v;
        }
        __syncthreads();

        // af = (m0*ew) @ fcw^T + fcb ; overwrite kaf as af[16][260]
        float* af = kaf;
        {
            float accv[16];
            float bias = fcb[t];
#pragma unroll
            for (int e = 0; e < 16; ++e) accv[e] = bias;
            const float4* w = (const float4*)(fcw + (size_t)t * 192);
            for (int i4 = 0; i4 < 48; ++i4) {
                float4 wv = w[i4];
#pragma unroll
                for (int e = 0; e < 16; ++e) {
                    float4 m4 = *(const float4*)&mwa[e][i4 * 4];
                    accv[e] = fmaf(m4.x, wv.x, fmaf(m4.y, wv.y, fmaf(m4.z, wv.z, fmaf(m4.w, wv.w, accv[e]))));
                }
            }
#pragma unroll
            for (int e = 0; e < 16; ++e) af[e * 260 + t] = accv[e];
        }
        __syncthreads();

        // LN(an) over S + smooth_leaky + logits dot alpha_dot
        if (t < 128) {
            int ek = t >> 3, h = t & 7;
            const float* row = &af[ek * 260 + h * 32];
            float mu = 0.0f, var = 0.0f;
#pragma unroll
            for (int s = 0; s < 32; ++s) mu += row[s];
            mu *= (1.0f / 32.0f);
#pragma unroll
            for (int s = 0; s < 32; ++s) { float dd = row[s] - mu; var = fmaf(dd, dd, var); }
            var *= (1.0f / 32.0f);
            float rs = rsqrtf(var + 1e-5f);
            float acc = 0.0f;
#pragma unroll
            for (int s = 0; s < 32; ++s) {
                float y = (row[s] - mu) * rs * an_g[s] + an_b[s];
                float sl = 0.6f * y + 0.4f * y * (2.0f * sigf(y) - 1.0f);
                acc = fmaf(sl, alpha_dot[h * 32 + s], acc);
            }
            logits_g[((size_t)(n * KNBR + kbase + ek)) * 8 + h] = maskk[ek] ? -1e9f : acc;
        }

        // rv MLP (layers 1-2) -> hb
        radial12(kk, j, &xe[kk][0], ha, hb,
                 rv_w1, rv_b1, rv_g1, rv_be1, rv_w2, rv_b2, rv_g2, rv_be2);

        // rv layer3 (16->256) -> global vw
        for (int r = 0; r < 16; ++r) {
            int oi = t + r * 256;
            int ek = oi >> 8, d = oi & 255;
            float acc = rv_b3[d];
#pragma unroll
            for (int i = 0; i < 16; ++i) acc = fmaf(hb[ek][i], rv_w3[d * 16 + i], acc);
            vw_g[((size_t)(n * KNBR + kbase + ek)) * 256 + d] = acc;
        }
    }
}

// ---------------- K4: softmax over K + alpha-weighted aggregation ----------------
__global__ __launch_bounds__(256) void k4_agg(
    const float* __restrict__ logits_g, const float* __restrict__ vw_g,
    const int* __restrict__ f_idx, const float* __restrict__ clus,
    float* __restrict__ outpre)
{
    __shared__ float lg[32][8];
    __shared__ float al[32][8];
    __shared__ int idxk[32];
    int n = blockIdx.x, t = threadIdx.x;
    if (t < 32) idxk[t] = f_idx[n * KNBR + t];
    {
        int k = t >> 3, h = t & 7;
        lg[k][h] = logits_g[((size_t)(n * KNBR + k)) * 8 + h];
    }
    __syncthreads();
    if (t < 8) {
        int h = t;
        float mx = -1e30f;
        for (int k = 0; k < 32; ++k) mx = fmaxf(mx, lg[k][h]);
        float sum = 0.0f;
        for (int k = 0; k < 32; ++k) { float e = __expf(lg[k][h] - mx); al[k][h] = e; sum += e; }
        float inv = 1.0f / sum;
        for (int k = 0; k < 32; ++k) al[k][h] *= inv;
    }
    __syncthreads();
    int c = t, h = c >> 5;
    float acc[9];
#pragma unroll
    for (int m = 0; m < 9; ++m) acc[m] = 0.0f;
    for (int k = 0; k < 32; ++k) {
        float wv = al[k][h] * vw_g[((size_t)(n * KNBR + k)) * 256 + c];
        const float* crow = clus + (size_t)idxk[k] * 2304 + c;
#pragma unroll
        for (int m = 0; m < 9; ++m) acc[m] = fmaf(wv, crow[m * 256], acc[m]);
    }
#pragma unroll
    for (int m = 0; m < 9; ++m) outpre[((size_t)n * 9 + m) * 256 + c] = acc[m];
}

// ---------------- K5: final so3_linear with wz (+bz on l=0), in-place on d_out ----------------
__global__ __launch_bounds__(256) void k5_final(
    const float* __restrict__ wz, const float* __restrict__ bz,
    float* __restrict__ io)
{
    __shared__ __align__(16) float X[32][256];
    __shared__ int rr[32];
    int b = blockIdx.x, t = threadIdx.x;
    int l, vr0, nm, moff;
    if (b < 64)       { l = 0; vr0 = b * 32;         nm = 1; moff = 0; }
    else if (b < 256) { l = 1; vr0 = (b - 64) * 32;  nm = 3; moff = 1; }
    else              { l = 2; vr0 = (b - 256) * 32; nm = 5; moff = 4; }
    if (t < 32) {
        int vr = vr0 + t;
        int n = vr / nm, m = moff + vr % nm;
        rr[t] = n * 9 + m;
    }
    __syncthreads();
    for (int e = t; e < 32 * 256; e += 256) {
        int r = e >> 8, c = e & 255;
        X[r][c] = io[(size_t)rr[r] * 256 + c];
    }
    __syncthreads();
    int d = t;
    float acc[32];
    float bias = (l == 0) ? bz[d] : 0.0f;
#pragma unroll
    for (int r = 0; r < 32; ++r) acc[r] = bias;
    const float4* w = (const float4*)(wz + ((size_t)l * 256 + d) * 256);
    for (int c4 = 0; c4 < 64; ++c4) {
        float4 wv = w[c4];
#pragma unroll
        for (int r = 0; r < 32; ++r) {
            float4 x4 = *(const float4*)&X[r][c4 * 4];
            acc[r] = fmaf(x4.x, wv.x, fmaf(x4.y, wv.y, fmaf(x4.z, wv.z, fmaf(x4.w, wv.w, acc[r]))));
        }
    }
#pragma unroll
    for (int r = 0; r < 32; ++r) io[(size_t)rr[r] * 256 + d] = acc[r];
}

// ---------------- launch ----------------
extern "C" void kernel_launch(void* const* d_in, const int* in_sizes, int n_in,
                              void* d_out, int out_size, void* d_ws, size_t ws_size,
                              hipStream_t stream)
{
    (void)in_sizes; (void)n_in; (void)out_size; (void)ws_size;

    const float* node_irreps = (const float*)d_in[1];
    const float* edge_vec    = (const float*)d_in[3];
    const float* attn_weight = (const float*)d_in[4];
    const int*   atom_num    = (const int*)d_in[5];
    const void*  attn_mask   = d_in[6];
    const int*   f_idx       = (const int*)d_in[7];
    const float* clus        = (const float*)d_in[8];
    const float* tgt_emb     = (const float*)d_in[9];
    const float* W_dot       = (const float*)d_in[10];
    const float* b_dot       = (const float*)d_in[11];
    const float* rm0_w1 = (const float*)d_in[12];
    const float* rm0_b1 = (const float*)d_in[13];
    const float* rm0_g1 = (const float*)d_in[14];
    const float* rm0_be1 = (const float*)d_in[15];
    const float* rm0_w2 = (const float*)d_in[16];
    const float* rm0_b2 = (const float*)d_in[17];
    const float* rm0_g2 = (const float*)d_in[18];
    const float* rm0_be2 = (const float*)d_in[19];
    const float* rm0_w3 = (const float*)d_in[20];
    const float* rm0_b3 = (const float*)d_in[21];
    const float* fcw = (const float*)d_in[22];
    const float* fcb = (const float*)d_in[23];
    const float* an_g = (const float*)d_in[24];
    const float* an_b = (const float*)d_in[25];
    const float* alpha_dot = (const float*)d_in[26];
    const float* rv_w1 = (const float*)d_in[27];
    const float* rv_b1 = (const float*)d_in[28];
    const float* rv_g1 = (const float*)d_in[29];
    const float* rv_be1 = (const float*)d_in[30];
    const float* rv_w2 = (const float*)d_in[31];
    const float* rv_b2 = (const float*)d_in[32];
    const float* rv_g2 = (const float*)d_in[33];
    const float* rv_be2 = (const float*)d_in[34];
    const float* rv_w3 = (const float*)d_in[35];
    const float* rv_b3 = (const float*)d_in[36];
    const float* wz = (const float*)d_in[37];
    const float* bz = (const float*)d_in[38];

    float* ws = (float*)d_ws;
    int* flag = (int*)d_ws;
    float* q_ws   = ws + 16;
    float* key_ws = q_ws + (size_t)NNODE * 9 * 32;
    float* logits = key_ws + (size_t)MCLUS * 9 * 32;
    float* vw     = logits + (size_t)NNODE * KNBR * 8;
    float* outpre = (float*)d_out;

    k0_detect<<<1, 256, 0, stream>>>((const unsigned int*)attn_mask, flag);
    k1_so3qk<<<1152, 256, 0, stream>>>(node_irreps, clus, W_dot, b_dot, q_ws, key_ws);
    k2_edge<<<NNODE, 256, 0, stream>>>(
        attn_weight, attn_mask, flag, f_idx, edge_vec, atom_num, tgt_emb, clus,
        q_ws, key_ws,
        rm0_w1, rm0_b1, rm0_g1, rm0_be1, rm0_w2, rm0_b2, rm0_g2, rm0_be2, rm0_w3, rm0_b3,
        fcw, fcb, an_g, an_b, alpha_dot,
        rv_w1, rv_b1, rv_g1, rv_be1, rv_w2, rv_b2, rv_g2, rv_be2, rv_w3, rv_b3,
        logits, vw);
    k4_agg<<<NNODE, 256, 0, stream>>>(logits, vw, f_idx, clus, outpre);
    k5_final<<<576, 256, 0, stream>>>(wz, bz, outpre);
}

// Round 2
// 1160.763 us; speedup vs baseline: 1.0718x; 1.0718x over previous
//
#include <hip/hip_runtime.h>
#include <math.h>

#define NNODE 2048
#define MCLUS 2048
#define KNBR  32
#define CDIM  256
#define HHEAD 8

__device__ __forceinline__ float sigf(float x) { return 1.0f / (1.0f + __expf(-x)); }

// ---------------- K0: detect attn_mask storage layout ----------------
__global__ void k0_detect(const unsigned int* __restrict__ mw, int* __restrict__ flag) {
    __shared__ int votes[2];
    int t = threadIdx.x;
    if (t < 2) votes[t] = 0;
    __syncthreads();
    int vb = 0, vf = 0;
    for (int i = t; i < (NNODE * KNBR) / 4; i += blockDim.x) {
        unsigned int w = mw[i];
        if (w == 0x3F800000u) vf = 1;
        else if (w > 1u) vb = 1;
    }
    if (vb) atomicOr(&votes[0], 1);
    if (vf) atomicOr(&votes[1], 1);
    __syncthreads();
    if (t == 0) flag[0] = votes[1] ? 2 : (votes[0] ? 1 : 0);
}

__device__ __forceinline__ bool edge_masked(const void* mp, int mode, int e) {
    if (mode == 1) return ((const unsigned char*)mp)[e] != 0;
    if (mode == 2) return ((const float*)mp)[e] != 0.0f;
    return ((const int*)mp)[e] != 0;
}

// ---------------- Kpre: fold tgt/cl_scal parts of radial layer-1 ----------------
// TA[256][32], CA[2048][32]; slot = mlp*16+j (mlp 0=rm0, 1=rv)
__global__ __launch_bounds__(256) void kpre(
    const float* __restrict__ tgt_emb, const float* __restrict__ clus,
    const float* __restrict__ rm0_w1, const float* __restrict__ rv_w1,
    float* __restrict__ TA, float* __restrict__ CA)
{
    int b = blockIdx.x, t = threadIdx.x;
    int slot = t & 31, j = slot & 15, mlp = slot >> 4;
    const float* w1 = mlp ? rv_w1 : rm0_w1;
    if (b < 32) {
        int a = b * 8 + (t >> 5);
        const float* x = tgt_emb + (size_t)a * 128;
        const float* w = w1 + j * 416 + 32;
        float acc = 0.0f;
        for (int i = 0; i < 128; i += 4)
            acc = fmaf(x[i], w[i], fmaf(x[i+1], w[i+1], fmaf(x[i+2], w[i+2], fmaf(x[i+3], w[i+3], acc))));
        TA[a * 32 + slot] = acc;
    } else {
        int m = (b - 32) * 8 + (t >> 5);
        const float* x = clus + (size_t)m * 2304;
        const float* w = w1 + j * 416 + 160;
        float acc = 0.0f;
        for (int i = 0; i < 256; i += 4)
            acc = fmaf(x[i], w[i], fmaf(x[i+1], w[i+1], fmaf(x[i+2], w[i+2], fmaf(x[i+3], w[i+3], acc))));
        CA[m * 32 + slot] = acc;
    }
}

// ---------------- K1: so3_linear for q (nodes) and key (clusters) ----------------
__global__ __launch_bounds__(256) void k1_so3qk(
    const float* __restrict__ nodei, const float* __restrict__ clus,
    const float* __restrict__ W_dot, const float* __restrict__ b_dot,
    float* __restrict__ q_ws, float* __restrict__ key_ws)
{
    __shared__ __align__(16) float X[32][256];
    __shared__ int rx[32], rmm[32];
    int b = blockIdx.x, t = threadIdx.x;
    int l, vr0, nm, moff;
    if (b < 128)      { l = 0; vr0 = b * 32;         nm = 1; moff = 0; }
    else if (b < 512) { l = 1; vr0 = (b - 128) * 32; nm = 3; moff = 1; }
    else              { l = 2; vr0 = (b - 512) * 32; nm = 5; moff = 4; }
    if (t < 32) {
        int vr = vr0 + t;
        rx[t] = vr / nm;
        rmm[t] = moff + vr % nm;
    }
    __syncthreads();
    for (int e = t; e < 32 * 256; e += 256) {
        int r = e >> 8, c = e & 255;
        int x = rx[r], m = rmm[r];
        const float* src = (x < NNODE) ? (nodei + ((size_t)x * 9 + m) * 256)
                                       : (clus + ((size_t)(x - NNODE) * 9 + m) * 256);
        X[r][c] = src[c];
    }
    __syncthreads();
    int d = t & 31, rg = t >> 5;
    int r0 = rg * 4;
    const float4* wrow = (const float4*)(W_dot + ((size_t)l * 32 + d) * 256);
    float acc[4];
    float bd = (l == 0) ? b_dot[d] : 0.0f;
#pragma unroll
    for (int jj = 0; jj < 4; ++jj) acc[jj] = bd;
    for (int c4 = 0; c4 < 64; ++c4) {
        float4 w = wrow[c4];
#pragma unroll
        for (int jj = 0; jj < 4; ++jj) {
            float4 x4 = *(const float4*)&X[r0 + jj][c4 * 4];
            acc[jj] = fmaf(x4.x, w.x, fmaf(x4.y, w.y, fmaf(x4.z, w.z, fmaf(x4.w, w.w, acc[jj]))));
        }
    }
#pragma unroll
    for (int jj = 0; jj < 4; ++jj) {
        int r = r0 + jj;
        int x = rx[r], m = rmm[r];
        float* dst = (x < NNODE) ? (q_ws + ((size_t)x * 9 + m) * 32)
                                 : (key_ws + ((size_t)(x - NNODE) * 9 + m) * 32);
        dst[d] = acc[jj];
    }
}

// ---------------- K2: fused per-node edge pipeline (wave-parallel MLPs) ----------------
__device__ __forceinline__ float lnsilu16(float x, float g, float b) {
    float s = x;
#pragma unroll
    for (int m = 1; m < 16; m <<= 1) s += __shfl_xor(s, m, 16);
    float mu = s * 0.0625f;
    float d = x - mu;
    float s2 = d * d;
#pragma unroll
    for (int m = 1; m < 16; m <<= 1) s2 += __shfl_xor(s2, m, 16);
    float y = d * rsqrtf(s2 * 0.0625f + 1e-5f) * g + b;
    return y * sigf(y);
}

__global__ __launch_bounds__(256, 2) void k2_edge(
    const float* __restrict__ attn_weight, const void* __restrict__ mask,
    const int* __restrict__ mflag,
    const int* __restrict__ f_idx, const float* __restrict__ edge_vec,
    const int* __restrict__ atom_num,
    const float* __restrict__ q_ws, const float* __restrict__ key_ws,
    const float* __restrict__ TA, const float* __restrict__ CA,
    const float* __restrict__ rm0_w1, const float* __restrict__ rm0_b1,
    const float* __restrict__ rm0_g1, const float* __restrict__ rm0_be1,
    const float* __restrict__ rm0_w2, const float* __restrict__ rm0_b2,
    const float* __restrict__ rm0_g2, const float* __restrict__ rm0_be2,
    const float* __restrict__ rm0_w3, const float* __restrict__ rm0_b3,
    const float* __restrict__ fcw, const float* __restrict__ fcb,
    const float* __restrict__ an_g, const float* __restrict__ an_b,
    const float* __restrict__ alpha_dot,
    const float* __restrict__ rv_w1, const float* __restrict__ rv_b1,
    const float* __restrict__ rv_g1, const float* __restrict__ rv_be1,
    const float* __restrict__ rv_w2, const float* __restrict__ rv_b2,
    const float* __restrict__ rv_g2, const float* __restrict__ rv_be2,
    const float* __restrict__ rv_w3, const float* __restrict__ rv_b3,
    float* __restrict__ logits_g, float* __restrict__ vw_g)
{
    __shared__ float qn[288];
    __shared__ float Ts[32];
    __shared__ float shS[32][9];
    __shared__ float awS[32][33];
    __shared__ float caS[32][33];
    __shared__ __align__(16) float mwaS[32][196];
    __shared__ __align__(16) float afT[32][257];
    __shared__ int idxk[32], maskk[32];

    int n = blockIdx.x, t = threadIdx.x;
    int mode = mflag[0];

    for (int i = t; i < 288; i += 256) qn[i] = q_ws[(size_t)n * 288 + i];
    if (t < 32) {
        int an = atom_num[n];
        Ts[t] = TA[an * 32 + t];
        int e = n * KNBR + t;
        idxk[t] = f_idx[e];
        maskk[t] = edge_masked(mask, mode, e) ? 1 : 0;
        float vx = edge_vec[(size_t)e * 3 + 0];
        float vy = edge_vec[(size_t)e * 3 + 1];
        float vz = edge_vec[(size_t)e * 3 + 2];
        float inv = 1.0f / (sqrtf(vx * vx + vy * vy + vz * vz) + 1e-12f);
        float x = vx * inv, y = vy * inv, z = vz * inv;
        shS[t][0] = 0.28209479177387814f;
        shS[t][1] = 0.4886025119029199f * y;
        shS[t][2] = 0.4886025119029199f * z;
        shS[t][3] = 0.4886025119029199f * x;
        shS[t][4] = 1.0925484305920792f * x * y;
        shS[t][5] = 1.0925484305920792f * y * z;
        shS[t][6] = 0.31539156525252005f * (3.0f * z * z - 1.0f);
        shS[t][7] = 1.0925484305920792f * x * z;
        shS[t][8] = 0.5462742152960396f * (x * x - y * y);
    }
    __syncthreads();
    for (int e2 = t; e2 < 1024; e2 += 256) {
        int ek = e2 >> 5, i = e2 & 31;
        awS[ek][i] = maskk[ek] ? 0.0f : attn_weight[((size_t)(n * KNBR + ek)) * 32 + i];
        caS[ek][i] = CA[(size_t)idxk[ek] * 32 + i];
    }
    __syncthreads();

    int g = t >> 4, j = t & 15;

    for (int ee = 0; ee < 2; ++ee) {
        int e = g + ee * 16;
        int idx = idxk[e];
        // ---- layer 1 (aw part only; tgt/cl folded via Ts/caS) ----
        float accm = rm0_b1[j] + Ts[j] + caS[e][j];
        float accv = rv_b1[j] + Ts[16 + j] + caS[e][16 + j];
        const float* w1m = rm0_w1 + j * 416;
        const float* w1v = rv_w1 + j * 416;
#pragma unroll
        for (int i = 0; i < 32; i += 4) {
            float a0 = awS[e][i], a1 = awS[e][i + 1], a2 = awS[e][i + 2], a3 = awS[e][i + 3];
            accm = fmaf(a0, w1m[i], fmaf(a1, w1m[i+1], fmaf(a2, w1m[i+2], fmaf(a3, w1m[i+3], accm))));
            accv = fmaf(a0, w1v[i], fmaf(a1, w1v[i+1], fmaf(a2, w1v[i+2], fmaf(a3, w1v[i+3], accv))));
        }
        float hm = lnsilu16(accm, rm0_g1[j], rm0_be1[j]);
        float hv = lnsilu16(accv, rv_g1[j], rv_be1[j]);
        // ---- layer 2 ----
        float am2 = rm0_b2[j], av2 = rv_b2[j];
#pragma unroll
        for (int i = 0; i < 16; ++i) {
            am2 = fmaf(__shfl(hm, i, 16), rm0_w2[j * 16 + i], am2);
            av2 = fmaf(__shfl(hv, i, 16), rv_w2[j * 16 + i], av2);
        }
        float h2m = lnsilu16(am2, rm0_g2[j], rm0_be2[j]);
        float h2v = lnsilu16(av2, rv_g2[j], rv_be2[j]);

        const float* keyrow = key_ws + (size_t)idx * 288;

        // ---- rm0 layer 3 + m0 dot -> mwaS ----
        {
            float h16[16];
#pragma unroll
            for (int i = 0; i < 16; ++i) h16[i] = __shfl(h2m, i, 16);
#pragma unroll
            for (int r = 0; r < 12; ++r) {
                int d = r * 16 + j;
                const float* w3 = rm0_w3 + d * 16;
                float ew = rm0_b3[d];
#pragma unroll
                for (int i = 0; i < 16; ++i) ew = fmaf(h16[i], w3[i], ew);
                int c = ((r & 1) << 4) + j;   // d & 31
                int bb = r >> 1;              // d >> 5
                float m0v;
                if (bb == 0)      m0v = qn[c] * shS[e][0];
                else if (bb == 1) m0v = qn[32 + c] * shS[e][1] + qn[64 + c] * shS[e][2]
                                      + qn[96 + c] * shS[e][3];
                else if (bb == 2) m0v = qn[128 + c] * shS[e][4] + qn[160 + c] * shS[e][5]
                                      + qn[192 + c] * shS[e][6] + qn[224 + c] * shS[e][7]
                                      + qn[256 + c] * shS[e][8];
                else if (bb == 3) m0v = keyrow[c] * shS[e][0];
                else if (bb == 4) m0v = keyrow[32 + c] * shS[e][1] + keyrow[64 + c] * shS[e][2]
                                      + keyrow[96 + c] * shS[e][3];
                else              m0v = keyrow[128 + c] * shS[e][4] + keyrow[160 + c] * shS[e][5]
                                      + keyrow[192 + c] * shS[e][6] + keyrow[224 + c] * shS[e][7]
                                      + keyrow[256 + c] * shS[e][8];
                mwaS[e][d] = ew * m0v;
            }
        }
        // ---- rv layer 3 -> vw global ----
        {
            float h16[16];
#pragma unroll
            for (int i = 0; i < 16; ++i) h16[i] = __shfl(h2v, i, 16);
            float* vwrow = vw_g + ((size_t)(n * KNBR + e)) * 256;
#pragma unroll
            for (int r = 0; r < 16; ++r) {
                int d = r * 16 + j;
                const float* w3 = rv_w3 + d * 16;
                float acc = rv_b3[d];
#pragma unroll
                for (int i = 0; i < 16; ++i) acc = fmaf(h16[i], w3[i], acc);
                vwrow[d] = acc;
            }
        }
    }
    __syncthreads();

    // ---- af GEMM: [32 edges x 192] @ fcw^T -> afT[s][e*8+h] ----
    {
        float accv[32];
        float bias = fcb[t];
#pragma unroll
        for (int e = 0; e < 32; ++e) accv[e] = bias;
        const float4* w = (const float4*)(fcw + (size_t)t * 192);
        for (int i4 = 0; i4 < 48; ++i4) {
            float4 wv = w[i4];
#pragma unroll
            for (int e = 0; e < 32; ++e) {
                float4 m4 = *(const float4*)&mwaS[e][i4 * 4];
                accv[e] = fmaf(m4.x, wv.x, fmaf(m4.y, wv.y, fmaf(m4.z, wv.z, fmaf(m4.w, wv.w, accv[e]))));
            }
        }
        int h = t >> 5, s = t & 31;
#pragma unroll
        for (int e = 0; e < 32; ++e) afT[s][e * 8 + h] = accv[e];
    }
    __syncthreads();

    // ---- LN + smooth_leaky + logits ----
    {
        int e = t >> 3, h = t & 7;
        float vals[32];
        float mu = 0.0f;
#pragma unroll
        for (int s = 0; s < 32; ++s) { vals[s] = afT[s][t]; mu += vals[s]; }
        mu *= (1.0f / 32.0f);
        float var = 0.0f;
#pragma unroll
        for (int s = 0; s < 32; ++s) { float dd = vals[s] - mu; var = fmaf(dd, dd, var); }
        var *= (1.0f / 32.0f);
        float rs = rsqrtf(var + 1e-5f);
        float acc = 0.0f;
#pragma unroll
        for (int s = 0; s < 32; ++s) {
            float y = (vals[s] - mu) * rs * an_g[s] + an_b[s];
            float sl = 0.6f * y + 0.4f * y * (2.0f * sigf(y) - 1.0f);
            acc = fmaf(sl, alpha_dot[h * 32 + s], acc);
        }
        logits_g[((size_t)(n * KNBR + e)) * 8 + h] = maskk[e] ? -1e9f : acc;
    }
}

// ---------------- K4: softmax over K + alpha-weighted aggregation ----------------
__global__ __launch_bounds__(256) void k4_agg(
    const float* __restrict__ logits_g, const float* __restrict__ vw_g,
    const int* __restrict__ f_idx, const float* __restrict__ clus,
    float* __restrict__ outpre)
{
    __shared__ float lg[32][8];
    __shared__ float al[32][8];
    __shared__ int idxk[32];
    int n = blockIdx.x, t = threadIdx.x;
    if (t < 32) idxk[t] = f_idx[n * KNBR + t];
    {
        int k = t >> 3, h = t & 7;
        lg[k][h] = logits_g[((size_t)(n * KNBR + k)) * 8 + h];
    }
    __syncthreads();
    if (t < 8) {
        int h = t;
        float mx = -1e30f;
        for (int k = 0; k < 32; ++k) mx = fmaxf(mx, lg[k][h]);
        float sum = 0.0f;
        for (int k = 0; k < 32; ++k) { float e = __expf(lg[k][h] - mx); al[k][h] = e; sum += e; }
        float inv = 1.0f / sum;
        for (int k = 0; k < 32; ++k) al[k][h] *= inv;
    }
    __syncthreads();
    int c = t, h = c >> 5;
    float acc[9];
#pragma unroll
    for (int m = 0; m < 9; ++m) acc[m] = 0.0f;
    for (int k = 0; k < 32; ++k) {
        float wv = al[k][h] * vw_g[((size_t)(n * KNBR + k)) * 256 + c];
        const float* crow = clus + (size_t)idxk[k] * 2304 + c;
#pragma unroll
        for (int m = 0; m < 9; ++m) acc[m] = fmaf(wv, crow[m * 256], acc[m]);
    }
#pragma unroll
    for (int m = 0; m < 9; ++m) outpre[((size_t)n * 9 + m) * 256 + c] = acc[m];
}

// ---------------- K5: final so3_linear with wz (+bz on l=0), in-place on d_out ----------------
__global__ __launch_bounds__(256) void k5_final(
    const float* __restrict__ wz, const float* __restrict__ bz,
    float* __restrict__ io)
{
    __shared__ __align__(16) float X[32][256];
    __shared__ int rr[32];
    int b = blockIdx.x, t = threadIdx.x;
    int l, vr0, nm, moff;
    if (b < 64)       { l = 0; vr0 = b * 32;         nm = 1; moff = 0; }
    else if (b < 256) { l = 1; vr0 = (b - 64) * 32;  nm = 3; moff = 1; }
    else              { l = 2; vr0 = (b - 256) * 32; nm = 5; moff = 4; }
    if (t < 32) {
        int vr = vr0 + t;
        int n = vr / nm, m = moff + vr % nm;
        rr[t] = n * 9 + m;
    }
    __syncthreads();
    for (int e = t; e < 32 * 256; e += 256) {
        int r = e >> 8, c = e & 255;
        X[r][c] = io[(size_t)rr[r] * 256 + c];
    }
    __syncthreads();
    int d = t;
    float acc[32];
    float bias = (l == 0) ? bz[d] : 0.0f;
#pragma unroll
    for (int r = 0; r < 32; ++r) acc[r] = bias;
    const float4* w = (const float4*)(wz + ((size_t)l * 256 + d) * 256);
    for (int c4 = 0; c4 < 64; ++c4) {
        float4 wv = w[c4];
#pragma unroll
        for (int r = 0; r < 32; ++r) {
            float4 x4 = *(const float4*)&X[r][c4 * 4];
            acc[r] = fmaf(x4.x, wv.x, fmaf(x4.y, wv.y, fmaf(x4.z, wv.z, fmaf(x4.w, wv.w, acc[r]))));
        }
    }
#pragma unroll
    for (int r = 0; r < 32; ++r) io[(size_t)rr[r] * 256 + d] = acc[r];
}

// ---------------- launch ----------------
extern "C" void kernel_launch(void* const* d_in, const int* in_sizes, int n_in,
                              void* d_out, int out_size, void* d_ws, size_t ws_size,
                              hipStream_t stream)
{
    (void)in_sizes; (void)n_in; (void)out_size; (void)ws_size;

    const float* node_irreps = (const float*)d_in[1];
    const float* edge_vec    = (const float*)d_in[3];
    const float* attn_weight = (const float*)d_in[4];
    const int*   atom_num    = (const int*)d_in[5];
    const void*  attn_mask   = d_in[6];
    const int*   f_idx       = (const int*)d_in[7];
    const float* clus        = (const float*)d_in[8];
    const float* tgt_emb     = (const float*)d_in[9];
    const float* W_dot       = (const float*)d_in[10];
    const float* b_dot       = (const float*)d_in[11];
    const float* rm0_w1 = (const float*)d_in[12];
    const float* rm0_b1 = (const float*)d_in[13];
    const float* rm0_g1 = (const float*)d_in[14];
    const float* rm0_be1 = (const float*)d_in[15];
    const float* rm0_w2 = (const float*)d_in[16];
    const float* rm0_b2 = (const float*)d_in[17];
    const float* rm0_g2 = (const float*)d_in[18];
    const float* rm0_be2 = (const float*)d_in[19];
    const float* rm0_w3 = (const float*)d_in[20];
    const float* rm0_b3 = (const float*)d_in[21];
    const float* fcw = (const float*)d_in[22];
    const float* fcb = (const float*)d_in[23];
    const float* an_g = (const float*)d_in[24];
    const float* an_b = (const float*)d_in[25];
    const float* alpha_dot = (const float*)d_in[26];
    const float* rv_w1 = (const float*)d_in[27];
    const float* rv_b1 = (const float*)d_in[28];
    const float* rv_g1 = (const float*)d_in[29];
    const float* rv_be1 = (const float*)d_in[30];
    const float* rv_w2 = (const float*)d_in[31];
    const float* rv_b2 = (const float*)d_in[32];
    const float* rv_g2 = (const float*)d_in[33];
    const float* rv_be2 = (const float*)d_in[34];
    const float* rv_w3 = (const float*)d_in[35];
    const float* rv_b3 = (const float*)d_in[36];
    const float* wz = (const float*)d_in[37];
    const float* bz = (const float*)d_in[38];

    float* ws = (float*)d_ws;
    int* flag = (int*)d_ws;
    float* q_ws   = ws + 16;
    float* key_ws = q_ws + (size_t)NNODE * 9 * 32;
    float* logits = key_ws + (size_t)MCLUS * 9 * 32;
    float* vw     = logits + (size_t)NNODE * KNBR * 8;
    float* TA_ws  = vw + (size_t)NNODE * KNBR * 256;
    float* CA_ws  = TA_ws + 256 * 32;
    float* outpre = (float*)d_out;

    k0_detect<<<1, 256, 0, stream>>>((const unsigned int*)attn_mask, flag);
    kpre<<<288, 256, 0, stream>>>(tgt_emb, clus, rm0_w1, rv_w1, TA_ws, CA_ws);
    k1_so3qk<<<1152, 256, 0, stream>>>(node_irreps, clus, W_dot, b_dot, q_ws, key_ws);
    k2_edge<<<NNODE, 256, 0, stream>>>(
        attn_weight, attn_mask, flag, f_idx, edge_vec, atom_num,
        q_ws, key_ws, TA_ws, CA_ws,
        rm0_w1, rm0_b1, rm0_g1, rm0_be1, rm0_w2, rm0_b2, rm0_g2, rm0_be2, rm0_w3, rm0_b3,
        fcw, fcb, an_g, an_b, alpha_dot,
        rv_w1, rv_b1, rv_g1, rv_be1, rv_w2, rv_b2, rv_g2, rv_be2, rv_w3, rv_b3,
        logits, vw);
    k4_agg<<<NNODE, 256, 0, stream>>>(logits, vw, f_idx, clus, outpre);
    k5_final<<<576, 256, 0, stream>>>(wz, bz, outpre);
}

// Round 3
// 795.769 us; speedup vs baseline: 1.5634x; 1.4587x over previous
//
#include <hip/hip_runtime.h>
#include <math.h>

#define NNODE 2048
#define MCLUS 2048
#define KNBR  32
#define CDIM  256
#define HHEAD 8

__device__ __forceinline__ float sigf(float x) { return 1.0f / (1.0f + __expf(-x)); }

// ---------------- K0: detect attn_mask storage layout ----------------
// mode 0 = int32 (0/1), mode 1 = raw bool bytes, mode 2 = float32 (0.0/1.0)
__global__ void k0_detect(const unsigned int* __restrict__ mw, int* __restrict__ flag) {
    int i = blockIdx.x * blockDim.x + threadIdx.x;   // 16384 threads, 1 word each
    unsigned int w = mw[i];
    int vb = (w != 0u && w != 1u && w != 0x3F800000u) ? 1 : 0;
    int vf = (w == 0x3F800000u) ? 1 : 0;
    unsigned long long bal_b = __ballot(vb);
    unsigned long long bal_f = __ballot(vf);
    if ((threadIdx.x & 63) == 0) {
        if (bal_b) atomicOr(flag, 1);
        if (bal_f) atomicOr(flag, 2);
    }
}

__device__ __forceinline__ bool edge_masked(const void* mp, int mode, int e) {
    if (mode & 2) return ((const float*)mp)[e] != 0.0f;
    if (mode & 1) return ((const unsigned char*)mp)[e] != 0;
    return ((const int*)mp)[e] != 0;
}

// ---------------- Kpre: fold tgt/cl_scal parts of radial layer-1 ----------------
// TA[256][32], CA[2048][32]; slot = mlp*16+j (mlp 0=rm0, 1=rv)
__global__ __launch_bounds__(256) void kpre(
    const float* __restrict__ tgt_emb, const float* __restrict__ clus,
    const float* __restrict__ rm0_w1, const float* __restrict__ rv_w1,
    float* __restrict__ TA, float* __restrict__ CA)
{
    int b = blockIdx.x, t = threadIdx.x;
    int slot = t & 31, j = slot & 15, mlp = slot >> 4;
    const float* w1 = mlp ? rv_w1 : rm0_w1;
    if (b < 32) {
        int a = b * 8 + (t >> 5);
        const float* x = tgt_emb + (size_t)a * 128;
        const float* w = w1 + j * 416 + 32;
        float acc = 0.0f;
        for (int i = 0; i < 128; i += 4)
            acc = fmaf(x[i], w[i], fmaf(x[i+1], w[i+1], fmaf(x[i+2], w[i+2], fmaf(x[i+3], w[i+3], acc))));
        TA[a * 32 + slot] = acc;
    } else {
        int m = (b - 32) * 8 + (t >> 5);
        const float* x = clus + (size_t)m * 2304;
        const float* w = w1 + j * 416 + 160;
        float acc = 0.0f;
        for (int i = 0; i < 256; i += 4)
            acc = fmaf(x[i], w[i], fmaf(x[i+1], w[i+1], fmaf(x[i+2], w[i+2], fmaf(x[i+3], w[i+3], acc))));
        CA[m * 32 + slot] = acc;
    }
}

// ---------------- K1: so3_linear for q (nodes) and key (clusters) ----------------
__global__ __launch_bounds__(256) void k1_so3qk(
    const float* __restrict__ nodei, const float* __restrict__ clus,
    const float* __restrict__ W_dot, const float* __restrict__ b_dot,
    float* __restrict__ q_ws, float* __restrict__ key_ws)
{
    __shared__ __align__(16) float X[32][256];
    __shared__ int rx[32], rmm[32];
    int b = blockIdx.x, t = threadIdx.x;
    int l, vr0, nm, moff;
    if (b < 128)      { l = 0; vr0 = b * 32;         nm = 1; moff = 0; }
    else if (b < 512) { l = 1; vr0 = (b - 128) * 32; nm = 3; moff = 1; }
    else              { l = 2; vr0 = (b - 512) * 32; nm = 5; moff = 4; }
    if (t < 32) {
        int vr = vr0 + t;
        rx[t] = vr / nm;
        rmm[t] = moff + vr % nm;
    }
    __syncthreads();
    for (int e = t; e < 32 * 256; e += 256) {
        int r = e >> 8, c = e & 255;
        int x = rx[r], m = rmm[r];
        const float* src = (x < NNODE) ? (nodei + ((size_t)x * 9 + m) * 256)
                                       : (clus + ((size_t)(x - NNODE) * 9 + m) * 256);
        X[r][c] = src[c];
    }
    __syncthreads();
    int d = t & 31, rg = t >> 5;
    int r0 = rg * 4;
    const float4* wrow = (const float4*)(W_dot + ((size_t)l * 32 + d) * 256);
    float acc[4];
    float bd = (l == 0) ? b_dot[d] : 0.0f;
#pragma unroll
    for (int jj = 0; jj < 4; ++jj) acc[jj] = bd;
    for (int c4 = 0; c4 < 64; ++c4) {
        float4 w = wrow[c4];
#pragma unroll
        for (int jj = 0; jj < 4; ++jj) {
            float4 x4 = *(const float4*)&X[r0 + jj][c4 * 4];
            acc[jj] = fmaf(x4.x, w.x, fmaf(x4.y, w.y, fmaf(x4.z, w.z, fmaf(x4.w, w.w, acc[jj]))));
        }
    }
#pragma unroll
    for (int jj = 0; jj < 4; ++jj) {
        int r = r0 + jj;
        int x = rx[r], m = rmm[r];
        float* dst = (x < NNODE) ? (q_ws + ((size_t)x * 9 + m) * 32)
                                 : (key_ws + ((size_t)(x - NNODE) * 9 + m) * 32);
        dst[d] = acc[jj];
    }
}

// ---------------- K2: fully fused per-node pipeline ----------------
__device__ __forceinline__ float lnsilu16(float x, float g, float b) {
    float s = x;
#pragma unroll
    for (int m = 1; m < 16; m <<= 1) s += __shfl_xor(s, m, 16);
    float mu = s * 0.0625f;
    float d = x - mu;
    float s2 = d * d;
#pragma unroll
    for (int m = 1; m < 16; m <<= 1) s2 += __shfl_xor(s2, m, 16);
    float y = d * rsqrtf(s2 * 0.0625f + 1e-5f) * g + b;
    return y * sigf(y);
}

__global__ __launch_bounds__(256, 4) void k2_fused(
    const float* __restrict__ attn_weight, const void* __restrict__ mask,
    const int* __restrict__ mflag,
    const int* __restrict__ f_idx, const float* __restrict__ edge_vec,
    const int* __restrict__ atom_num, const float* __restrict__ clus,
    const float* __restrict__ q_ws, const float* __restrict__ key_ws,
    const float* __restrict__ TA, const float* __restrict__ CA,
    const float* __restrict__ rm0_w1, const float* __restrict__ rm0_b1,
    const float* __restrict__ rm0_g1, const float* __restrict__ rm0_be1,
    const float* __restrict__ rm0_w2, const float* __restrict__ rm0_b2,
    const float* __restrict__ rm0_g2, const float* __restrict__ rm0_be2,
    const float* __restrict__ rm0_w3, const float* __restrict__ rm0_b3,
    const float* __restrict__ fcw, const float* __restrict__ fcb,
    const float* __restrict__ an_g, const float* __restrict__ an_b,
    const float* __restrict__ alpha_dot,
    const float* __restrict__ rv_w1, const float* __restrict__ rv_b1,
    const float* __restrict__ rv_g1, const float* __restrict__ rv_be1,
    const float* __restrict__ rv_w2, const float* __restrict__ rv_b2,
    const float* __restrict__ rv_g2, const float* __restrict__ rv_be2,
    const float* __restrict__ rv_w3, const float* __restrict__ rv_b3,
    float* __restrict__ outpre)
{
    __shared__ float qn[288];
    __shared__ float Ts[32];
    __shared__ float shS[32][9];
    __shared__ float awS[32][33];
    __shared__ float caS[32][33];
    __shared__ __align__(16) float mwaS[32][196];
    __shared__ float h2vS[32][17];
    __shared__ float lgS[32][8];
    __shared__ int idxk[32], maskk[32];

    int n = blockIdx.x, t = threadIdx.x;
    int mode = mflag[0];

    for (int i = t; i < 288; i += 256) qn[i] = q_ws[(size_t)n * 288 + i];
    if (t < 32) {
        int an = atom_num[n];
        Ts[t] = TA[an * 32 + t];
        int e = n * KNBR + t;
        idxk[t] = f_idx[e];
        maskk[t] = edge_masked(mask, mode, e) ? 1 : 0;
        float vx = edge_vec[(size_t)e * 3 + 0];
        float vy = edge_vec[(size_t)e * 3 + 1];
        float vz = edge_vec[(size_t)e * 3 + 2];
        float inv = 1.0f / (sqrtf(vx * vx + vy * vy + vz * vz) + 1e-12f);
        float x = vx * inv, y = vy * inv, z = vz * inv;
        shS[t][0] = 0.28209479177387814f;
        shS[t][1] = 0.4886025119029199f * y;
        shS[t][2] = 0.4886025119029199f * z;
        shS[t][3] = 0.4886025119029199f * x;
        shS[t][4] = 1.0925484305920792f * x * y;
        shS[t][5] = 1.0925484305920792f * y * z;
        shS[t][6] = 0.31539156525252005f * (3.0f * z * z - 1.0f);
        shS[t][7] = 1.0925484305920792f * x * z;
        shS[t][8] = 0.5462742152960396f * (x * x - y * y);
    }
    __syncthreads();
    for (int e2 = t; e2 < 1024; e2 += 256) {
        int ek = e2 >> 5, i = e2 & 31;
        awS[ek][i] = maskk[ek] ? 0.0f : attn_weight[((size_t)(n * KNBR + ek)) * 32 + i];
        caS[ek][i] = CA[(size_t)idxk[ek] * 32 + i];
    }
    __syncthreads();

    // ================= phase A: edge MLPs (wave-parallel, 16-lane groups) =========
    {
        int g = t >> 4, j = t & 15;
        for (int ee = 0; ee < 2; ++ee) {
            int e = g + ee * 16;
            int idx = idxk[e];
            float accm = rm0_b1[j] + Ts[j] + caS[e][j];
            float accv = rv_b1[j] + Ts[16 + j] + caS[e][16 + j];
            const float* w1m = rm0_w1 + j * 416;
            const float* w1v = rv_w1 + j * 416;
#pragma unroll
            for (int i = 0; i < 32; i += 4) {
                float a0 = awS[e][i], a1 = awS[e][i + 1], a2 = awS[e][i + 2], a3 = awS[e][i + 3];
                accm = fmaf(a0, w1m[i], fmaf(a1, w1m[i+1], fmaf(a2, w1m[i+2], fmaf(a3, w1m[i+3], accm))));
                accv = fmaf(a0, w1v[i], fmaf(a1, w1v[i+1], fmaf(a2, w1v[i+2], fmaf(a3, w1v[i+3], accv))));
            }
            float hm = lnsilu16(accm, rm0_g1[j], rm0_be1[j]);
            float hv = lnsilu16(accv, rv_g1[j], rv_be1[j]);
            float am2 = rm0_b2[j], av2 = rv_b2[j];
#pragma unroll
            for (int i = 0; i < 16; ++i) {
                am2 = fmaf(__shfl(hm, i, 16), rm0_w2[j * 16 + i], am2);
                av2 = fmaf(__shfl(hv, i, 16), rv_w2[j * 16 + i], av2);
            }
            float h2m = lnsilu16(am2, rm0_g2[j], rm0_be2[j]);
            float h2v = lnsilu16(av2, rv_g2[j], rv_be2[j]);
            h2vS[e][j] = h2v;

            const float* keyrow = key_ws + (size_t)idx * 288;
            float h16[16];
#pragma unroll
            for (int i = 0; i < 16; ++i) h16[i] = __shfl(h2m, i, 16);
#pragma unroll
            for (int r = 0; r < 12; ++r) {
                int d = r * 16 + j;
                const float* w3 = rm0_w3 + d * 16;
                float ew = rm0_b3[d];
#pragma unroll
                for (int i = 0; i < 16; ++i) ew = fmaf(h16[i], w3[i], ew);
                int c = ((r & 1) << 4) + j;   // d & 31
                int bb = r >> 1;              // d >> 5
                float m0v;
                if (bb == 0)      m0v = qn[c] * shS[e][0];
                else if (bb == 1) m0v = qn[32 + c] * shS[e][1] + qn[64 + c] * shS[e][2]
                                      + qn[96 + c] * shS[e][3];
                else if (bb == 2) m0v = qn[128 + c] * shS[e][4] + qn[160 + c] * shS[e][5]
                                      + qn[192 + c] * shS[e][6] + qn[224 + c] * shS[e][7]
                                      + qn[256 + c] * shS[e][8];
                else if (bb == 3) m0v = keyrow[c] * shS[e][0];
                else if (bb == 4) m0v = keyrow[32 + c] * shS[e][1] + keyrow[64 + c] * shS[e][2]
                                      + keyrow[96 + c] * shS[e][3];
                else              m0v = keyrow[128 + c] * shS[e][4] + keyrow[160 + c] * shS[e][5]
                                      + keyrow[192 + c] * shS[e][6] + keyrow[224 + c] * shS[e][7]
                                      + keyrow[256 + c] * shS[e][8];
                mwaS[e][d] = ew * m0v;
            }
        }
    }
    __syncthreads();

    // ================= phase B: af GEMM + LN + smooth_leaky + logits ==============
    // thread t = (h, s); per e the 32 s-values sit in 32 consecutive lanes.
    {
        int h = t >> 5, s = t & 31;
        float ang = an_g[s], anb = an_b[s], ad = alpha_dot[h * 32 + s];
        float bias = fcb[t];
        const float4* fr = (const float4*)(fcw + (size_t)t * 192);
#pragma unroll
        for (int chunk = 0; chunk < 2; ++chunk) {
            float acc[16];
#pragma unroll
            for (int e = 0; e < 16; ++e) acc[e] = bias;
            for (int i4 = 0; i4 < 48; ++i4) {
                float4 wv = fr[i4];
#pragma unroll
                for (int e = 0; e < 16; ++e) {
                    float4 m4 = *(const float4*)&mwaS[chunk * 16 + e][i4 * 4];
                    acc[e] = fmaf(m4.x, wv.x, fmaf(m4.y, wv.y, fmaf(m4.z, wv.z, fmaf(m4.w, wv.w, acc[e]))));
                }
            }
#pragma unroll
            for (int ee = 0; ee < 16; ++ee) {
                int e = chunk * 16 + ee;
                float v = acc[ee];
                float su = v;
#pragma unroll
                for (int m = 1; m < 32; m <<= 1) su += __shfl_xor(su, m, 32);
                float mu = su * (1.0f / 32.0f);
                float dd = v - mu;
                float s2 = dd * dd;
#pragma unroll
                for (int m = 1; m < 32; m <<= 1) s2 += __shfl_xor(s2, m, 32);
                float rs = rsqrtf(s2 * (1.0f / 32.0f) + 1e-5f);
                float y = dd * rs * ang + anb;
                float sl = 0.6f * y + 0.4f * y * (2.0f * sigf(y) - 1.0f);
                float lgv = sl * ad;
#pragma unroll
                for (int m = 1; m < 32; m <<= 1) lgv += __shfl_xor(lgv, m, 32);
                if (s == 0) lgS[e][h] = maskk[e] ? -1e9f : lgv;
            }
        }
    }
    __syncthreads();

    // ================= softmax over k (in place in lgS) ===========================
    if (t < 8) {
        int h = t;
        float mx = -1e30f;
#pragma unroll
        for (int k = 0; k < 32; ++k) mx = fmaxf(mx, lgS[k][h]);
        float sum = 0.0f;
        float ex[32];
#pragma unroll
        for (int k = 0; k < 32; ++k) { ex[k] = __expf(lgS[k][h] - mx); sum += ex[k]; }
        float inv = 1.0f / sum;
#pragma unroll
        for (int k = 0; k < 32; ++k) lgS[k][h] = ex[k] * inv;
    }
    __syncthreads();

    // ================= phase C: vw recompute + alpha aggregation ==================
    {
        int c = t, h = c >> 5;
        float b3c = rv_b3[c];
        float w3r[16];
        const float4* w3p = (const float4*)(rv_w3 + c * 16);
#pragma unroll
        for (int i4 = 0; i4 < 4; ++i4) {
            float4 w = w3p[i4];
            w3r[i4 * 4 + 0] = w.x; w3r[i4 * 4 + 1] = w.y;
            w3r[i4 * 4 + 2] = w.z; w3r[i4 * 4 + 3] = w.w;
        }
        float acc[9];
#pragma unroll
        for (int m = 0; m < 9; ++m) acc[m] = 0.0f;
        for (int k = 0; k < 32; ++k) {
            float a = lgS[k][h];
            float vw = b3c;
#pragma unroll
            for (int i = 0; i < 16; ++i) vw = fmaf(h2vS[k][i], w3r[i], vw);
            float av = a * vw;
            const float* crow = clus + (size_t)idxk[k] * 2304 + c;
#pragma unroll
            for (int m = 0; m < 9; ++m) acc[m] = fmaf(av, crow[m * 256], acc[m]);
        }
#pragma unroll
        for (int m = 0; m < 9; ++m) outpre[((size_t)n * 9 + m) * 256 + c] = acc[m];
    }
}

// ---------------- K5: final so3_linear with wz (+bz on l=0), in-place on d_out ----
__global__ __launch_bounds__(256) void k5_final(
    const float* __restrict__ wz, const float* __restrict__ bz,
    float* __restrict__ io)
{
    __shared__ __align__(16) float X[32][256];
    __shared__ int rr[32];
    int b = blockIdx.x, t = threadIdx.x;
    int l, vr0, nm, moff;
    if (b < 64)       { l = 0; vr0 = b * 32;         nm = 1; moff = 0; }
    else if (b < 256) { l = 1; vr0 = (b - 64) * 32;  nm = 3; moff = 1; }
    else              { l = 2; vr0 = (b - 256) * 32; nm = 5; moff = 4; }
    if (t < 32) {
        int vr = vr0 + t;
        int n = vr / nm, m = moff + vr % nm;
        rr[t] = n * 9 + m;
    }
    __syncthreads();
    for (int e = t; e < 32 * 256; e += 256) {
        int r = e >> 8, c = e & 255;
        X[r][c] = io[(size_t)rr[r] * 256 + c];
    }
    __syncthreads();
    int d = t;
    float acc[32];
    float bias = (l == 0) ? bz[d] : 0.0f;
#pragma unroll
    for (int r = 0; r < 32; ++r) acc[r] = bias;
    const float4* w = (const float4*)(wz + ((size_t)l * 256 + d) * 256);
    for (int c4 = 0; c4 < 64; ++c4) {
        float4 wv = w[c4];
#pragma unroll
        for (int r = 0; r < 32; ++r) {
            float4 x4 = *(const float4*)&X[r][c4 * 4];
            acc[r] = fmaf(x4.x, wv.x, fmaf(x4.y, wv.y, fmaf(x4.z, wv.z, fmaf(x4.w, wv.w, acc[r]))));
        }
    }
#pragma unroll
    for (int r = 0; r < 32; ++r) io[(size_t)rr[r] * 256 + d] = acc[r];
}

// ---------------- launch ----------------
extern "C" void kernel_launch(void* const* d_in, const int* in_sizes, int n_in,
                              void* d_out, int out_size, void* d_ws, size_t ws_size,
                              hipStream_t stream)
{
    (void)in_sizes; (void)n_in; (void)out_size; (void)ws_size;

    const float* node_irreps = (const float*)d_in[1];
    const float* edge_vec    = (const float*)d_in[3];
    const float* attn_weight = (const float*)d_in[4];
    const int*   atom_num    = (const int*)d_in[5];
    const void*  attn_mask   = d_in[6];
    const int*   f_idx       = (const int*)d_in[7];
    const float* clus        = (const float*)d_in[8];
    const float* tgt_emb     = (const float*)d_in[9];
    const float* W_dot       = (const float*)d_in[10];
    const float* b_dot       = (const float*)d_in[11];
    const float* rm0_w1 = (const float*)d_in[12];
    const float* rm0_b1 = (const float*)d_in[13];
    const float* rm0_g1 = (const float*)d_in[14];
    const float* rm0_be1 = (const float*)d_in[15];
    const float* rm0_w2 = (const float*)d_in[16];
    const float* rm0_b2 = (const float*)d_in[17];
    const float* rm0_g2 = (const float*)d_in[18];
    const float* rm0_be2 = (const float*)d_in[19];
    const float* rm0_w3 = (const float*)d_in[20];
    const float* rm0_b3 = (const float*)d_in[21];
    const float* fcw = (const float*)d_in[22];
    const float* fcb = (const float*)d_in[23];
    const float* an_g = (const float*)d_in[24];
    const float* an_b = (const float*)d_in[25];
    const float* alpha_dot = (const float*)d_in[26];
    const float* rv_w1 = (const float*)d_in[27];
    const float* rv_b1 = (const float*)d_in[28];
    const float* rv_g1 = (const float*)d_in[29];
    const float* rv_be1 = (const float*)d_in[30];
    const float* rv_w2 = (const float*)d_in[31];
    const float* rv_b2 = (const float*)d_in[32];
    const float* rv_g2 = (const float*)d_in[33];
    const float* rv_be2 = (const float*)d_in[34];
    const float* rv_w3 = (const float*)d_in[35];
    const float* rv_b3 = (const float*)d_in[36];
    const float* wz = (const float*)d_in[37];
    const float* bz = (const float*)d_in[38];

    float* ws = (float*)d_ws;
    int* flag = (int*)d_ws;
    float* q_ws   = ws + 16;
    float* key_ws = q_ws + (size_t)NNODE * 9 * 32;
    float* TA_ws  = key_ws + (size_t)MCLUS * 9 * 32;
    float* CA_ws  = TA_ws + 256 * 32;
    float* outpre = (float*)d_out;

    hipMemsetAsync(flag, 0, sizeof(int), stream);
    k0_detect<<<64, 256, 0, stream>>>((const unsigned int*)attn_mask, flag);
    kpre<<<288, 256, 0, stream>>>(tgt_emb, clus, rm0_w1, rv_w1, TA_ws, CA_ws);
    k1_so3qk<<<1152, 256, 0, stream>>>(node_irreps, clus, W_dot, b_dot, q_ws, key_ws);
    k2_fused<<<NNODE, 256, 0, stream>>>(
        attn_weight, attn_mask, flag, f_idx, edge_vec, atom_num, clus,
        q_ws, key_ws, TA_ws, CA_ws,
        rm0_w1, rm0_b1, rm0_g1, rm0_be1, rm0_w2, rm0_b2, rm0_g2, rm0_be2, rm0_w3, rm0_b3,
        fcw, fcb, an_g, an_b, alpha_dot,
        rv_w1, rv_b1, rv_g1, rv_be1, rv_w2, rv_b2, rv_g2, rv_be2, rv_w3, rv_b3,
        outpre);
    k5_final<<<576, 256, 0, stream>>>(wz, bz, outpre);
}